// Round 1
// 884.713 us; speedup vs baseline: 1.1384x; 1.1384x over previous
//
#include <hip/hip_runtime.h>
#include <hip/hip_bf16.h>

#define NB    8
#define NC    192
#define IMH   192
#define IMW   192
#define WSZ   8
#define SSZ   4
#define NHEAD 6
#define HDIM  32
#define NTOK  64
#define NWH   24
#define NWW   24

#define WQ_ELEMS (3 * NC * NC)   // 110592
#define WP_ELEMS (NC * NC)       // 36864

typedef __attribute__((ext_vector_type(8))) short short8;   // 8 bf16 = 4 VGPRs
typedef __attribute__((ext_vector_type(4))) float float4e;  // MFMA accumulator

__device__ __forceinline__ float bf2f(ushort u) {
    union { uint i; float f; } v; v.i = ((uint)u) << 16; return v.f;
}
__device__ __forceinline__ ushort f2bf(float f) {
    union { float f; uint i; } v; v.f = f;
    uint u = v.i;
    u += 0x7FFFu + ((u >> 16) & 1u);   // round-to-nearest-even
    return (ushort)(u >> 16);
}

// ---- kernel 1: convert f32 weights -> bf16 into workspace ----
__global__ __launch_bounds__(256)
void cvt_weights_kernel(const float* __restrict__ wq, const float* __restrict__ wp,
                        ushort* __restrict__ dst)
{
    const int i = (blockIdx.x * 256 + threadIdx.x) * 4;
    const float* src = (i < WQ_ELEMS) ? (wq + i) : (wp + (i - WQ_ELEMS));
    const float4 v = *(const float4*)src;
    ushort4 o;
    o.x = f2bf(v.x); o.y = f2bf(v.y); o.z = f2bf(v.z); o.w = f2bf(v.w);
    *(ushort4*)(dst + i) = o;
}

// ---- kernel 2: fully fused shifted-window attention. One block per window. ----
// 512 threads = 8 waves (2 waves/SIMD: the occupancy fix — LDS 138.5 KB keeps
// 1 block/CU, so the block itself must carry the latency-hiding waves).
// LDS:
//   sBiasF : 225*6 rel-bias table (f32)
//   sX     : [64][200] bf16 window input; reused as AOut for proj
//   sQ     : [6][64][40] bf16 Q (scaled); reused as OutL [64][200] bf16
//   sK     : [6][64][40] bf16
//   sVt    : [6][32][72] bf16 V transposed (hd-major)
//   sP     : [8 waves][16][72] bf16 softmax probs (wave-private, no barrier)
__global__ __launch_bounds__(512)
void swin_attn_kernel(const float* __restrict__ x,
                      const ushort* __restrict__ qkv_w,   // bf16 (from ws)
                      const float* __restrict__ qkv_b,
                      const ushort* __restrict__ proj_w,  // bf16 (from ws)
                      const float* __restrict__ proj_b,
                      const float* __restrict__ bias_t,
                      float* __restrict__ out)
{
    __shared__ float sBiasF[1350];
    __shared__ __align__(16) ushort sX[NTOK * 200];
    __shared__ __align__(16) ushort sQ[NHEAD * NTOK * 40];
    __shared__ __align__(16) ushort sK[NHEAD * NTOK * 40];
    __shared__ __align__(16) ushort sVt[NHEAD * HDIM * 72];
    __shared__ __align__(16) ushort sP[8 * 16 * 72];

    const int tid  = threadIdx.x;
    // XCD-aware swizzle (bijective: 4608 % 8 == 0). Each XCD gets a contiguous
    // raster chunk of windows -> adjacent windows' shared x-rows stay in its L2.
    const int blk  = (blockIdx.x & 7) * (NB * NWH * NWW / 8) + (blockIdx.x >> 3);
    const int b    = blk / (NWH * NWW);
    const int wIdx = blk % (NWH * NWW);
    const int wh   = wIdx / NWW;
    const int ww   = wIdx % NWW;

    const int wv   = tid >> 6;   // wave id 0..7
    const int ln   = tid & 63;
    const int quad = ln >> 4;    // 0..3
    const int l15  = ln & 15;
    const int mh   = wv >> 2;    // M-half 0..1 (GEMM phases)
    const int ng   = wv & 3;     // N-group 0..3 (GEMM phases)

    // ---- stage rel-bias table (f32) ----
    for (int i = tid; i < 1350; i += 512) sBiasF[i] = bias_t[i];

    // ---- stage shifted window into LDS (f32 -> bf16) ----
    // ch-fast thread map: a wave writes 64 consecutive ushorts per ds_write
    // (2 lanes/dword = conflict-free), vs 8-way conflicts of the ti-fast map.
    const int co0 = ww * WSZ + SSZ;        // 16B aligned
    const int co4 = (co0 + 4) % IMW;       // wrap lands at 0 (ww=23), aligned
    for (int r = tid; r < NC * WSZ; r += 512) {
        const int ti = r / NC;             // window row 0..7
        const int ch = r - ti * NC;        // channel 0..191
        const int ro = (wh * WSZ + ti + SSZ) % IMH;
        const float* src = x + (((size_t)b * NC + ch) * IMH + ro) * IMW;
        const float4 a0 = *(const float4*)(src + co0);
        const float4 a1 = *(const float4*)(src + co4);
        ushort* dst = &sX[(ti * 8) * 200 + ch];
        dst[0 * 200] = f2bf(a0.x);  dst[1 * 200] = f2bf(a0.y);
        dst[2 * 200] = f2bf(a0.z);  dst[3 * 200] = f2bf(a0.w);
        dst[4 * 200] = f2bf(a1.x);  dst[5 * 200] = f2bf(a1.y);
        dst[6 * 200] = f2bf(a1.z);  dst[7 * 200] = f2bf(a1.w);
    }
    __syncthreads();

    const float scale = 0.17677669529663687f;  // 32^-0.5
    const float4e zf = {0.f, 0.f, 0.f, 0.f};

    // ---- QKV GEMM: M=64 tok, K=192 ch, N=576.
    // Wave (mh, ng): M rows [32mh, 32mh+32), N-tiles [9ng, 9ng+9).
    for (int nt = 0; nt < 9; ++nt) {
        const int ocb = (ng * 9 + nt) * 16;
        const int oc  = ocb + l15;
        float4e acc[2] = {zf, zf};
        #pragma unroll
        for (int ks = 0; ks < 6; ++ks) {
            const int k0 = ks * 32 + quad * 8;
            const short8 bfr = *(const short8*)(qkv_w + (size_t)oc * NC + k0);
            #pragma unroll
            for (int mt = 0; mt < 2; ++mt) {
                const short8 afr = *(const short8*)(&sX[(mh * 32 + mt * 16 + l15) * 200 + k0]);
                acc[mt] = __builtin_amdgcn_mfma_f32_16x16x32_bf16(afr, bfr, acc[mt], 0, 0, 0);
            }
        }
        const float bias = qkv_b[oc];
        // each 16-wide N-tile is purely q, k, or v (192 boundary is a tile boundary)
        if (oc < 192) {
            const int h = oc >> 5, d = oc & 31;
            #pragma unroll
            for (int mt = 0; mt < 2; ++mt)
                #pragma unroll
                for (int r = 0; r < 4; ++r) {
                    const int token = mh * 32 + mt * 16 + quad * 4 + r;   // C-layout row
                    sQ[(h * 64 + token) * 40 + d] = f2bf((acc[mt][r] + bias) * scale);
                }
        } else if (oc < 384) {
            const int o = oc - 192, h = o >> 5, d = o & 31;
            #pragma unroll
            for (int mt = 0; mt < 2; ++mt)
                #pragma unroll
                for (int r = 0; r < 4; ++r) {
                    const int token = mh * 32 + mt * 16 + quad * 4 + r;
                    sK[(h * 64 + token) * 40 + d] = f2bf(acc[mt][r] + bias);
                }
        } else {
            const int o = oc - 384, h = o >> 5, d = o & 31;
            #pragma unroll
            for (int mt = 0; mt < 2; ++mt)
                #pragma unroll
                for (int r = 0; r < 4; ++r) {
                    const int token = mh * 32 + mt * 16 + quad * 4 + r;
                    sVt[(h * 32 + d) * 72 + token] = f2bf(acc[mt][r] + bias);
                }
        }
    }
    __syncthreads();

    // ---- attention: 24 units = 6 heads x 4 query-row stripes; 3 units/wave.
    // sP is wave-private -> no barriers inside the loop.
    #pragma unroll
    for (int i = 0; i < 3; ++i) {
        const int u  = wv * 3 + i;
        const int h  = u >> 2;     // head 0..5
        const int st = u & 3;      // query stripe 0..3

        // S = Q_stripe (16x32) . K^T (32x64)
        float4e s[4] = {zf, zf, zf, zf};
        const short8 qf = *(const short8*)(&sQ[(h * 64 + st * 16 + l15) * 40 + quad * 8]);
        #pragma unroll
        for (int ct = 0; ct < 4; ++ct) {
            const short8 kf = *(const short8*)(&sK[(h * 64 + ct * 16 + l15) * 40 + quad * 8]);
            s[ct] = __builtin_amdgcn_mfma_f32_16x16x32_bf16(qf, kf, s[ct], 0, 0, 0);
        }
        // + rel bias + shift mask (inline; only edge windows actually mask)
        #pragma unroll
        for (int ct = 0; ct < 4; ++ct) {
            const int kt = ct * 16 + l15;       // key token (C-layout col)
            const int rj = kt >> 3, cj = kt & 7;
            const int krow = wh * 8 + rj, kcol = ww * 8 + cj;
            const int bkr = (krow < 184) ? 0 : ((krow < 188) ? 1 : 2);
            const int bkc = (kcol < 184) ? 0 : ((kcol < 188) ? 1 : 2);
            const int cntk = bkr * 3 + bkc;
            #pragma unroll
            for (int r = 0; r < 4; ++r) {
                const int qt = st * 16 + quad * 4 + r;   // query token (C-layout row)
                const int ri = qt >> 3, ci = qt & 7;
                const int idx = (ri - rj + 7) * 15 + (ci - cj + 7);
                float v = s[ct][r] + sBiasF[idx * NHEAD + h];
                const int qrow = wh * 8 + ri, qcol = ww * 8 + ci;
                const int bqr = (qrow < 184) ? 0 : ((qrow < 188) ? 1 : 2);
                const int bqc = (qcol < 184) ? 0 : ((qcol < 188) ? 1 : 2);
                if (bqr * 3 + bqc != cntk) v -= 100.0f;
                s[ct][r] = v;
            }
        }
        // row softmax: row's 64 cols live in 4 regs x 16 lanes (same quad) -> shfl-xor
        float p[4][4];
        #pragma unroll
        for (int r = 0; r < 4; ++r) {
            float mx = fmaxf(fmaxf(s[0][r], s[1][r]), fmaxf(s[2][r], s[3][r]));
            #pragma unroll
            for (int m = 1; m < 16; m <<= 1) mx = fmaxf(mx, __shfl_xor(mx, m));
            float sum = 0.f;
            #pragma unroll
            for (int ct = 0; ct < 4; ++ct) { p[ct][r] = __expf(s[ct][r] - mx); sum += p[ct][r]; }
            #pragma unroll
            for (int m = 1; m < 16; m <<= 1) sum += __shfl_xor(sum, m);
            const float inv = 1.0f / sum;
            #pragma unroll
            for (int ct = 0; ct < 4; ++ct) p[ct][r] *= inv;
        }
        // P: C-layout -> LDS [16][72] (A-layout source), wave-private slab
        #pragma unroll
        for (int ct = 0; ct < 4; ++ct)
            #pragma unroll
            for (int r = 0; r < 4; ++r)
                sP[(wv * 16 + quad * 4 + r) * 72 + ct * 16 + l15] = f2bf(p[ct][r]);

        // O_stripe (16x32) = P (16x64) . V (64x32)
        float4e o0 = zf, o1 = zf;
        #pragma unroll
        for (int kb = 0; kb < 2; ++kb) {
            const int k0 = kb * 32 + quad * 8;
            const short8 pf = *(const short8*)(&sP[(wv * 16 + l15) * 72 + k0]);
            const short8 v0 = *(const short8*)(&sVt[(h * 32 + l15) * 72 + k0]);
            const short8 v1 = *(const short8*)(&sVt[(h * 32 + 16 + l15) * 72 + k0]);
            o0 = __builtin_amdgcn_mfma_f32_16x16x32_bf16(pf, v0, o0, 0, 0, 0);
            o1 = __builtin_amdgcn_mfma_f32_16x16x32_bf16(pf, v1, o1, 0, 0, 0);
        }
        // AOut[token][h*32 + d] into sX (Xw is dead after QKV GEMM)
        #pragma unroll
        for (int r = 0; r < 4; ++r) {
            const int token = st * 16 + quad * 4 + r;
            sX[token * 200 + h * 32 + l15]      = f2bf(o0[r]);
            sX[token * 200 + h * 32 + 16 + l15] = f2bf(o1[r]);
        }
    }
    __syncthreads();

    // ---- proj GEMM: M=64, K=192, N=192. Wave (mh, ng): 2 M-tiles x 3 N-tiles.
    for (int nt = 0; nt < 3; ++nt) {
        const int ocb = (ng * 3 + nt) * 16;
        const int oc  = ocb + l15;
        float4e acc[2] = {zf, zf};
        #pragma unroll
        for (int ks = 0; ks < 6; ++ks) {
            const int k0 = ks * 32 + quad * 8;
            const short8 bfr = *(const short8*)(proj_w + (size_t)oc * NC + k0);
            #pragma unroll
            for (int mt = 0; mt < 2; ++mt) {
                const short8 afr = *(const short8*)(&sX[(mh * 32 + mt * 16 + l15) * 200 + k0]);
                acc[mt] = __builtin_amdgcn_mfma_f32_16x16x32_bf16(afr, bfr, acc[mt], 0, 0, 0);
            }
        }
        const float pb = proj_b[oc];
        #pragma unroll
        for (int mt = 0; mt < 2; ++mt)
            #pragma unroll
            for (int r = 0; r < 4; ++r) {
                const int token = mh * 32 + mt * 16 + quad * 4 + r;
                sQ[token * 200 + oc] = f2bf(acc[mt][r] + pb);  // OutL reuses sQ
            }
    }
    __syncthreads();

    // ---- window reverse + roll back: bf16 LDS transpose -> f32 float4 stores ----
    for (int r = tid; r < NC * WSZ; r += 512) {
        const int ti = r / NC;
        const int ch = r - ti * NC;
        const int ro = (wh * WSZ + ti + SSZ) % IMH;
        float* dst = out + (((size_t)b * NC + ch) * IMH + ro) * IMW;
        const ushort* sp = &sQ[(ti * 8) * 200 + ch];
        float4 a0, a1;
        a0.x = bf2f(sp[0 * 200]);  a0.y = bf2f(sp[1 * 200]);
        a0.z = bf2f(sp[2 * 200]);  a0.w = bf2f(sp[3 * 200]);
        a1.x = bf2f(sp[4 * 200]);  a1.y = bf2f(sp[5 * 200]);
        a1.z = bf2f(sp[6 * 200]);  a1.w = bf2f(sp[7 * 200]);
        *(float4*)(dst + co0) = a0;
        *(float4*)(dst + co4) = a1;
    }
}

extern "C" void kernel_launch(void* const* d_in, const int* in_sizes, int n_in,
                              void* d_out, int out_size, void* d_ws, size_t ws_size,
                              hipStream_t stream) {
    const float* x      = (const float*)d_in[0];
    const float* qkv_w  = (const float*)d_in[1];
    const float* qkv_b  = (const float*)d_in[2];
    const float* proj_w = (const float*)d_in[3];
    const float* proj_b = (const float*)d_in[4];
    const float* bias_t = (const float*)d_in[5];
    float* out = (float*)d_out;
    (void)in_sizes; (void)n_in; (void)out_size; (void)ws_size;

    ushort* wq_bf = (ushort*)d_ws;            // 110592 bf16
    ushort* wp_bf = wq_bf + WQ_ELEMS;         // 36864 bf16

    // convert weights f32 -> bf16 (147456 elems, 4/thread)
    hipLaunchKernelGGL(cvt_weights_kernel, dim3((WQ_ELEMS + WP_ELEMS) / 4 / 256), dim3(256),
                       0, stream, qkv_w, proj_w, wq_bf);

    dim3 grid(NB * NWH * NWW);   // 4608 windows
    dim3 block(512);             // 8 waves = 2 waves/SIMD
    hipLaunchKernelGGL(swin_attn_kernel, grid, block, 0, stream,
                       x, wq_bf, qkv_b, wp_bf, proj_b, bias_t, out);
}

// Round 2
// 784.661 us; speedup vs baseline: 1.2836x; 1.1275x over previous
//
#include <hip/hip_runtime.h>
#include <hip/hip_bf16.h>

#define NB    8
#define NC    192
#define IMH   192
#define IMW   192
#define WSZ   8
#define SSZ   4
#define NHEAD 6
#define HDIM  32
#define NTOK  64
#define NWH   24
#define NWW   24

#define WQ_ELEMS (3 * NC * NC)   // 110592
#define WP_ELEMS (NC * NC)       // 36864

#define HW        (IMH * IMW)            // 36864
#define TOK_TOTAL (NB * HW)              // 294912
#define PLANE     ((size_t)TOK_TOTAL * 32)  // ushorts per qkv plane

typedef __attribute__((ext_vector_type(8))) short short8;   // 8 bf16 = 4 VGPRs
typedef __attribute__((ext_vector_type(4))) float float4e;  // MFMA accumulator

__device__ __forceinline__ float bf2f(ushort u) {
    union { uint i; float f; } v; v.i = ((uint)u) << 16; return v.f;
}
__device__ __forceinline__ ushort f2bf(float f) {
    union { float f; uint i; } v; v.f = f;
    uint u = v.i;
    u += 0x7FFFu + ((u >> 16) & 1u);   // round-to-nearest-even
    return (ushort)(u >> 16);
}

// ---- kernel 0: convert f32 weights -> bf16 into workspace ----
__global__ __launch_bounds__(256)
void cvt_weights_kernel(const float* __restrict__ wq, const float* __restrict__ wp,
                        ushort* __restrict__ dst)
{
    const int i = (blockIdx.x * 256 + threadIdx.x) * 4;
    const float* src = (i < WQ_ELEMS) ? (wq + i) : (wp + (i - WQ_ELEMS));
    const float4 v = *(const float4*)src;
    ushort4 o;
    o.x = f2bf(v.x); o.y = f2bf(v.y); o.z = f2bf(v.z); o.w = f2bf(v.w);
    *(ushort4*)(dst + i) = o;
}

// ============================ split pipeline ============================
// K1: QKV GEMM over raster tokens (shift is NOT applied here; QKV is pointwise
// so the roll commutes — K2 gathers shifted coords).
// Output layout: qkv[plane 0..17][B*HW][32] bf16, plane = oc>>5
// (planes 0-5 = Q heads (pre-scaled), 6-11 = K heads, 12-17 = V heads).
__global__ __launch_bounds__(256, 4)
void qkv_gemm_kernel(const float* __restrict__ x, const ushort* __restrict__ qkv_w,
                     const float* __restrict__ qkv_b, ushort* __restrict__ qkv)
{
    __shared__ __align__(16) ushort sX[NTOK * 200];      // [64 pix][192 ch]+pad
    __shared__ __align__(16) ushort sSlab[4][64][24];    // per-wave C transpose slab

    const int tid  = threadIdx.x;
    const int bid  = blockIdx.x;
    const int b    = bid / 576;
    const int pix0 = (bid % 576) * 64;                   // 64 consecutive pixels, no row straddle

    const int wv = tid >> 6, ln = tid & 63, quad = ln >> 4, l15 = ln & 15;

    // stage x[ch][pix0..+64) f32 -> sX[pix][ch] bf16. ch-fast lanes: LDS writes
    // conflict-free; global gather absorbed by L1/L2 (lines fully consumed).
    for (int i = tid; i < 3072; i += 256) {
        const int ch = i % 192;
        const int g  = i / 192;           // pixel group of 4
        const float4 a = *(const float4*)(x + (size_t)(b * NC + ch) * HW + pix0 + g * 4);
        ushort* dst = &sX[(g * 4) * 200 + ch];
        dst[0 * 200] = f2bf(a.x); dst[1 * 200] = f2bf(a.y);
        dst[2 * 200] = f2bf(a.z); dst[3 * 200] = f2bf(a.w);
    }
    __syncthreads();

    const float scale = 0.17677669529663687f;  // 32^-0.5 applied to Q
    const float4e zf = {0.f, 0.f, 0.f, 0.f};

    for (int nt = 0; nt < 9; ++nt) {
        const int ocb = (wv * 9 + nt) * 16;
        const int oc  = ocb + l15;
        float4e acc[4] = {zf, zf, zf, zf};
        #pragma unroll
        for (int ks = 0; ks < 6; ++ks) {
            const int k0 = ks * 32 + quad * 8;
            const short8 bfr = *(const short8*)(qkv_w + (size_t)oc * NC + k0);
            #pragma unroll
            for (int mt = 0; mt < 4; ++mt) {
                const short8 afr = *(const short8*)(&sX[(mt * 16 + l15) * 200 + k0]);
                acc[mt] = __builtin_amdgcn_mfma_f32_16x16x32_bf16(afr, bfr, acc[mt], 0, 0, 0);
            }
        }
        const float bias = qkv_b[oc];
        const bool  isQ  = (ocb < 192);
        #pragma unroll
        for (int mt = 0; mt < 4; ++mt)
            #pragma unroll
            for (int r = 0; r < 4; ++r) {
                const int token = mt * 16 + quad * 4 + r;
                float v = acc[mt][r] + bias;
                if (isQ) v *= scale;
                sSlab[wv][token][l15] = f2bf(v);
            }
        // wave-private slab -> global (vectorized 16B stores), plane layout
        const int p  = ocb >> 5;
        const int dh = (ocb >> 4) & 1;
        ushort* gbase = qkv + (size_t)p * PLANE + ((size_t)(b * HW + pix0)) * 32 + dh * 16;
        const ushort* srow = &sSlab[wv][ln][0];
        const short8 v0 = *(const short8*)(srow);
        const short8 v1 = *(const short8*)(srow + 8);
        *(short8*)(gbase + (size_t)ln * 32)     = v0;
        *(short8*)(gbase + (size_t)ln * 32 + 8) = v1;
    }
}

// K2: attention. One block (256 thr = 4 waves) per (window, head).
// LDS ~20 KB -> up to 6 blocks/CU. Each wave owns one 16-query stripe.
// bid mapping: XCD-chunked so each XCD owns one batch image, heads of a window adjacent.
__global__ __launch_bounds__(256, 6)
void attn_kernel(const ushort* __restrict__ qkv, const float* __restrict__ bias_t,
                 ushort* __restrict__ aout)
{
    __shared__ __align__(16) ushort sK[NTOK * 40];       // [64 tok][32 d]+pad; reused as AOut slab
    __shared__ __align__(16) ushort sVt[HDIM * 72];      // [32 d][64 tok]+pad
    __shared__ __align__(16) ushort sP[4][16 * 72];      // per-wave P slab
    __shared__ float sBiasH[225];

    const int bid  = blockIdx.x;
    const int xcd  = bid & 7;
    const int slot = bid >> 3;                 // 0..3455
    const int widx = xcd * 576 + slot / 6;     // window id; b == xcd
    const int h    = slot % 6;
    const int b    = widx / 576;
    const int wr   = widx % 576;
    const int wh   = wr / NWW;
    const int ww   = wr % NWW;

    const int tid = threadIdx.x;
    const int wv = tid >> 6, ln = tid & 63, quad = ln >> 4, l15 = ln & 15;

    const ushort* qP = qkv + (size_t)h * PLANE;
    const ushort* kP = qkv + (size_t)(6 + h) * PLANE;
    const ushort* vP = qkv + (size_t)(12 + h) * PLANE;
    const size_t  tb = (size_t)b * HW;

    // shifted pixel of window token t
    auto pixOf = [&](int t) {
        int ro = wh * 8 + (t >> 3) + SSZ; if (ro >= IMH) ro -= IMH;
        int co = ww * 8 + (t & 7)  + SSZ; if (co >= IMW) co -= IMW;
        return ro * IMW + co;
    };

    // Q fragment straight from global (issue early; no LDS dep)
    const int qtok = wv * 16 + l15;
    const int qpix = pixOf(qtok);
    const short8 qf = *(const short8*)(qP + (tb + qpix) * 32 + quad * 8);

    // stage K (row-major) and V (transposed) for this head
    {
        const int token = tid & 63, dq = tid >> 6;
        const int pix = pixOf(token);
        const short8 kv = *(const short8*)(kP + (tb + pix) * 32 + dq * 8);
        *(short8*)(&sK[token * 40 + dq * 8]) = kv;
        const short8 vv = *(const short8*)(vP + (tb + pix) * 32 + dq * 8);
        ushort* vd = &sVt[(dq * 8) * 72 + token];
        #pragma unroll
        for (int j = 0; j < 8; ++j) vd[j * 72] = (ushort)vv[j];
    }
    for (int i = tid; i < 225; i += 256) sBiasH[i] = bias_t[i * 6 + h];
    __syncthreads();

    const float4e zf = {0.f, 0.f, 0.f, 0.f};
    const int st = wv;   // query stripe

    // S = Q_stripe (16x32) . K^T (32x64)
    float4e s[4] = {zf, zf, zf, zf};
    #pragma unroll
    for (int ct = 0; ct < 4; ++ct) {
        const short8 kf = *(const short8*)(&sK[(ct * 16 + l15) * 40 + quad * 8]);
        s[ct] = __builtin_amdgcn_mfma_f32_16x16x32_bf16(qf, kf, s[ct], 0, 0, 0);
    }
    // + rel bias + shift mask
    #pragma unroll
    for (int ct = 0; ct < 4; ++ct) {
        const int kt = ct * 16 + l15;
        const int rj = kt >> 3, cj = kt & 7;
        const int krow = wh * 8 + rj, kcol = ww * 8 + cj;
        const int bkr = (krow < 184) ? 0 : ((krow < 188) ? 1 : 2);
        const int bkc = (kcol < 184) ? 0 : ((kcol < 188) ? 1 : 2);
        const int cntk = bkr * 3 + bkc;
        #pragma unroll
        for (int r = 0; r < 4; ++r) {
            const int qt = st * 16 + quad * 4 + r;
            const int ri = qt >> 3, ci = qt & 7;
            const int idx = (ri - rj + 7) * 15 + (ci - cj + 7);
            float v = s[ct][r] + sBiasH[idx];
            const int qrow = wh * 8 + ri, qcol = ww * 8 + ci;
            const int bqr = (qrow < 184) ? 0 : ((qrow < 188) ? 1 : 2);
            const int bqc = (qcol < 184) ? 0 : ((qcol < 188) ? 1 : 2);
            if (bqr * 3 + bqc != cntk) v -= 100.0f;
            s[ct][r] = v;
        }
    }
    // row softmax: 64 cols live in 4 regs x 16 lanes (same quad) -> shfl-xor
    float p[4][4];
    #pragma unroll
    for (int r = 0; r < 4; ++r) {
        float mx = fmaxf(fmaxf(s[0][r], s[1][r]), fmaxf(s[2][r], s[3][r]));
        #pragma unroll
        for (int m = 1; m < 16; m <<= 1) mx = fmaxf(mx, __shfl_xor(mx, m));
        float sum = 0.f;
        #pragma unroll
        for (int ct = 0; ct < 4; ++ct) { p[ct][r] = __expf(s[ct][r] - mx); sum += p[ct][r]; }
        #pragma unroll
        for (int m = 1; m < 16; m <<= 1) sum += __shfl_xor(sum, m);
        const float inv = 1.0f / sum;
        #pragma unroll
        for (int ct = 0; ct < 4; ++ct) p[ct][r] *= inv;
    }
    // P: C-layout -> wave-private LDS slab (A-layout source)
    #pragma unroll
    for (int ct = 0; ct < 4; ++ct)
        #pragma unroll
        for (int r = 0; r < 4; ++r)
            sP[wv][(quad * 4 + r) * 72 + ct * 16 + l15] = f2bf(p[ct][r]);

    // O_stripe (16x32) = P (16x64) . V (64x32)
    float4e o0 = zf, o1 = zf;
    #pragma unroll
    for (int kb = 0; kb < 2; ++kb) {
        const int k0 = kb * 32 + quad * 8;
        const short8 pf = *(const short8*)(&sP[wv][l15 * 72 + k0]);
        const short8 v0 = *(const short8*)(&sVt[l15 * 72 + k0]);
        const short8 v1 = *(const short8*)(&sVt[(16 + l15) * 72 + k0]);
        o0 = __builtin_amdgcn_mfma_f32_16x16x32_bf16(pf, v0, o0, 0, 0, 0);
        o1 = __builtin_amdgcn_mfma_f32_16x16x32_bf16(pf, v1, o1, 0, 0, 0);
    }
    __syncthreads();            // everyone done reading sK/sVt
    // O C-layout -> AOut slab (reuse sK), then vectorized global write
    ushort* sAOut = sK;
    #pragma unroll
    for (int r = 0; r < 4; ++r) {
        const int token = st * 16 + quad * 4 + r;
        sAOut[token * 40 + l15]      = f2bf(o0[r]);
        sAOut[token * 40 + 16 + l15] = f2bf(o1[r]);
    }
    __syncthreads();
    {
        const int token = tid >> 2, c4 = tid & 3;
        const int pix = pixOf(token);
        const short8 ov = *(const short8*)(&sAOut[token * 40 + c4 * 8]);
        // scatter back to raster coords (this resolves the inverse roll)
        *(short8*)(aout + (tb + pix) * 192 + h * 32 + c4 * 8) = ov;
    }
}

// K3: proj GEMM, raster tokens. A rows are contiguous [token][192] bf16 ->
// fragments loaded straight from global, held in regs (reused across all nt).
__global__ __launch_bounds__(256, 5)
void proj_kernel(const ushort* __restrict__ aout, const ushort* __restrict__ proj_w,
                 const float* __restrict__ proj_b, float* __restrict__ out)
{
    __shared__ __align__(16) ushort sOutL[NTOK * 210];   // pad 210: 2-way-max on col reads

    const int tid  = threadIdx.x;
    const int bid  = blockIdx.x;
    const int b    = bid / 576;
    const int pix0 = (bid % 576) * 64;

    const int wv = tid >> 6, ln = tid & 63, quad = ln >> 4, l15 = ln & 15;
    const int mh = wv >> 1;        // M-half
    const int ng = wv & 1;         // N-group (96 cols each)

    const ushort* abase = aout + ((size_t)(b * HW + pix0)) * 192;
    short8 afr[2][6];
    #pragma unroll
    for (int mt = 0; mt < 2; ++mt)
        #pragma unroll
        for (int ks = 0; ks < 6; ++ks)
            afr[mt][ks] = *(const short8*)(abase + (mh * 32 + mt * 16 + l15) * 192
                                                 + ks * 32 + quad * 8);

    const float4e zf = {0.f, 0.f, 0.f, 0.f};
    for (int nt = 0; nt < 6; ++nt) {
        const int ocb = (ng * 6 + nt) * 16;
        const int oc  = ocb + l15;
        float4e acc[2] = {zf, zf};
        #pragma unroll
        for (int ks = 0; ks < 6; ++ks) {
            const short8 bfr = *(const short8*)(proj_w + (size_t)oc * NC + ks * 32 + quad * 8);
            acc[0] = __builtin_amdgcn_mfma_f32_16x16x32_bf16(afr[0][ks], bfr, acc[0], 0, 0, 0);
            acc[1] = __builtin_amdgcn_mfma_f32_16x16x32_bf16(afr[1][ks], bfr, acc[1], 0, 0, 0);
        }
        const float pb = proj_b[oc];
        #pragma unroll
        for (int mt = 0; mt < 2; ++mt)
            #pragma unroll
            for (int r = 0; r < 4; ++r) {
                const int token = mh * 32 + mt * 16 + quad * 4 + r;
                sOutL[token * 210 + oc] = f2bf(acc[mt][r] + pb);
            }
    }
    __syncthreads();

    // epilogue: transpose to [ch][pix] f32, pixel-fast lanes -> coalesced stores
    for (int i = tid; i < 3072; i += 256) {
        const int fg = i & 15;       // pixel group of 4 (lanes consecutive)
        const int ch = i >> 4;
        const ushort* sp = &sOutL[(fg * 4) * 210 + ch];
        float4 a;
        a.x = bf2f(sp[0 * 210]); a.y = bf2f(sp[1 * 210]);
        a.z = bf2f(sp[2 * 210]); a.w = bf2f(sp[3 * 210]);
        *(float4*)(out + (size_t)(b * NC + ch) * HW + pix0 + fg * 4) = a;
    }
}

// ==================== fallback: round-1 fused kernel ====================
// (used only if workspace is too small for the split pipeline's intermediates)
__global__ __launch_bounds__(512)
void swin_attn_kernel(const float* __restrict__ x,
                      const ushort* __restrict__ qkv_w,
                      const float* __restrict__ qkv_b,
                      const ushort* __restrict__ proj_w,
                      const float* __restrict__ proj_b,
                      const float* __restrict__ bias_t,
                      float* __restrict__ out)
{
    __shared__ float sBiasF[1350];
    __shared__ __align__(16) ushort sX[NTOK * 200];
    __shared__ __align__(16) ushort sQ[NHEAD * NTOK * 40];
    __shared__ __align__(16) ushort sK[NHEAD * NTOK * 40];
    __shared__ __align__(16) ushort sVt[NHEAD * HDIM * 72];
    __shared__ __align__(16) ushort sP[8 * 16 * 72];

    const int tid  = threadIdx.x;
    const int blk  = (blockIdx.x & 7) * (NB * NWH * NWW / 8) + (blockIdx.x >> 3);
    const int b    = blk / (NWH * NWW);
    const int wIdx = blk % (NWH * NWW);
    const int wh   = wIdx / NWW;
    const int ww   = wIdx % NWW;

    const int wv   = tid >> 6;
    const int ln   = tid & 63;
    const int quad = ln >> 4;
    const int l15  = ln & 15;
    const int mh   = wv >> 2;
    const int ng   = wv & 3;

    for (int i = tid; i < 1350; i += 512) sBiasF[i] = bias_t[i];

    const int co0 = ww * WSZ + SSZ;
    const int co4 = (co0 + 4) % IMW;
    for (int r = tid; r < NC * WSZ; r += 512) {
        const int ti = r / NC;
        const int ch = r - ti * NC;
        const int ro = (wh * WSZ + ti + SSZ) % IMH;
        const float* src = x + (((size_t)b * NC + ch) * IMH + ro) * IMW;
        const float4 a0 = *(const float4*)(src + co0);
        const float4 a1 = *(const float4*)(src + co4);
        ushort* dst = &sX[(ti * 8) * 200 + ch];
        dst[0 * 200] = f2bf(a0.x);  dst[1 * 200] = f2bf(a0.y);
        dst[2 * 200] = f2bf(a0.z);  dst[3 * 200] = f2bf(a0.w);
        dst[4 * 200] = f2bf(a1.x);  dst[5 * 200] = f2bf(a1.y);
        dst[6 * 200] = f2bf(a1.z);  dst[7 * 200] = f2bf(a1.w);
    }
    __syncthreads();

    const float scale = 0.17677669529663687f;
    const float4e zf = {0.f, 0.f, 0.f, 0.f};

    for (int nt = 0; nt < 9; ++nt) {
        const int ocb = (ng * 9 + nt) * 16;
        const int oc  = ocb + l15;
        float4e acc[2] = {zf, zf};
        #pragma unroll
        for (int ks = 0; ks < 6; ++ks) {
            const int k0 = ks * 32 + quad * 8;
            const short8 bfr = *(const short8*)(qkv_w + (size_t)oc * NC + k0);
            #pragma unroll
            for (int mt = 0; mt < 2; ++mt) {
                const short8 afr = *(const short8*)(&sX[(mh * 32 + mt * 16 + l15) * 200 + k0]);
                acc[mt] = __builtin_amdgcn_mfma_f32_16x16x32_bf16(afr, bfr, acc[mt], 0, 0, 0);
            }
        }
        const float bias = qkv_b[oc];
        if (oc < 192) {
            const int h = oc >> 5, d = oc & 31;
            #pragma unroll
            for (int mt = 0; mt < 2; ++mt)
                #pragma unroll
                for (int r = 0; r < 4; ++r) {
                    const int token = mh * 32 + mt * 16 + quad * 4 + r;
                    sQ[(h * 64 + token) * 40 + d] = f2bf((acc[mt][r] + bias) * scale);
                }
        } else if (oc < 384) {
            const int o = oc - 192, h = o >> 5, d = o & 31;
            #pragma unroll
            for (int mt = 0; mt < 2; ++mt)
                #pragma unroll
                for (int r = 0; r < 4; ++r) {
                    const int token = mh * 32 + mt * 16 + quad * 4 + r;
                    sK[(h * 64 + token) * 40 + d] = f2bf(acc[mt][r] + bias);
                }
        } else {
            const int o = oc - 384, h = o >> 5, d = o & 31;
            #pragma unroll
            for (int mt = 0; mt < 2; ++mt)
                #pragma unroll
                for (int r = 0; r < 4; ++r) {
                    const int token = mh * 32 + mt * 16 + quad * 4 + r;
                    sVt[(h * 32 + d) * 72 + token] = f2bf(acc[mt][r] + bias);
                }
        }
    }
    __syncthreads();

    #pragma unroll
    for (int i = 0; i < 3; ++i) {
        const int u  = wv * 3 + i;
        const int h  = u >> 2;
        const int st = u & 3;

        float4e s[4] = {zf, zf, zf, zf};
        const short8 qf = *(const short8*)(&sQ[(h * 64 + st * 16 + l15) * 40 + quad * 8]);
        #pragma unroll
        for (int ct = 0; ct < 4; ++ct) {
            const short8 kf = *(const short8*)(&sK[(h * 64 + ct * 16 + l15) * 40 + quad * 8]);
            s[ct] = __builtin_amdgcn_mfma_f32_16x16x32_bf16(qf, kf, s[ct], 0, 0, 0);
        }
        #pragma unroll
        for (int ct = 0; ct < 4; ++ct) {
            const int kt = ct * 16 + l15;
            const int rj = kt >> 3, cj = kt & 7;
            const int krow = wh * 8 + rj, kcol = ww * 8 + cj;
            const int bkr = (krow < 184) ? 0 : ((krow < 188) ? 1 : 2);
            const int bkc = (kcol < 184) ? 0 : ((kcol < 188) ? 1 : 2);
            const int cntk = bkr * 3 + bkc;
            #pragma unroll
            for (int r = 0; r < 4; ++r) {
                const int qt = st * 16 + quad * 4 + r;
                const int ri = qt >> 3, ci = qt & 7;
                const int idx = (ri - rj + 7) * 15 + (ci - cj + 7);
                float v = s[ct][r] + sBiasF[idx * NHEAD + h];
                const int qrow = wh * 8 + ri, qcol = ww * 8 + ci;
                const int bqr = (qrow < 184) ? 0 : ((qrow < 188) ? 1 : 2);
                const int bqc = (qcol < 184) ? 0 : ((qcol < 188) ? 1 : 2);
                if (bqr * 3 + bqc != cntk) v -= 100.0f;
                s[ct][r] = v;
            }
        }
        float p[4][4];
        #pragma unroll
        for (int r = 0; r < 4; ++r) {
            float mx = fmaxf(fmaxf(s[0][r], s[1][r]), fmaxf(s[2][r], s[3][r]));
            #pragma unroll
            for (int m = 1; m < 16; m <<= 1) mx = fmaxf(mx, __shfl_xor(mx, m));
            float sum = 0.f;
            #pragma unroll
            for (int ct = 0; ct < 4; ++ct) { p[ct][r] = __expf(s[ct][r] - mx); sum += p[ct][r]; }
            #pragma unroll
            for (int m = 1; m < 16; m <<= 1) sum += __shfl_xor(sum, m);
            const float inv = 1.0f / sum;
            #pragma unroll
            for (int ct = 0; ct < 4; ++ct) p[ct][r] *= inv;
        }
        #pragma unroll
        for (int ct = 0; ct < 4; ++ct)
            #pragma unroll
            for (int r = 0; r < 4; ++r)
                sP[(wv * 16 + quad * 4 + r) * 72 + ct * 16 + l15] = f2bf(p[ct][r]);

        float4e o0 = zf, o1 = zf;
        #pragma unroll
        for (int kb = 0; kb < 2; ++kb) {
            const int k0 = kb * 32 + quad * 8;
            const short8 pf = *(const short8*)(&sP[(wv * 16 + l15) * 72 + k0]);
            const short8 v0 = *(const short8*)(&sVt[(h * 32 + l15) * 72 + k0]);
            const short8 v1 = *(const short8*)(&sVt[(h * 32 + 16 + l15) * 72 + k0]);
            o0 = __builtin_amdgcn_mfma_f32_16x16x32_bf16(pf, v0, o0, 0, 0, 0);
            o1 = __builtin_amdgcn_mfma_f32_16x16x32_bf16(pf, v1, o1, 0, 0, 0);
        }
        #pragma unroll
        for (int r = 0; r < 4; ++r) {
            const int token = st * 16 + quad * 4 + r;
            sX[token * 200 + h * 32 + l15]      = f2bf(o0[r]);
            sX[token * 200 + h * 32 + 16 + l15] = f2bf(o1[r]);
        }
    }
    __syncthreads();

    for (int nt = 0; nt < 3; ++nt) {
        const int ocb = (ng * 3 + nt) * 16;
        const int oc  = ocb + l15;
        float4e acc[2] = {zf, zf};
        #pragma unroll
        for (int ks = 0; ks < 6; ++ks) {
            const int k0 = ks * 32 + quad * 8;
            const short8 bfr = *(const short8*)(proj_w + (size_t)oc * NC + k0);
            #pragma unroll
            for (int mt = 0; mt < 2; ++mt) {
                const short8 afr = *(const short8*)(&sX[(mh * 32 + mt * 16 + l15) * 200 + k0]);
                acc[mt] = __builtin_amdgcn_mfma_f32_16x16x32_bf16(afr, bfr, acc[mt], 0, 0, 0);
            }
        }
        const float pb = proj_b[oc];
        #pragma unroll
        for (int mt = 0; mt < 2; ++mt)
            #pragma unroll
            for (int r = 0; r < 4; ++r) {
                const int token = mh * 32 + mt * 16 + quad * 4 + r;
                sQ[token * 200 + oc] = f2bf(acc[mt][r] + pb);
            }
    }
    __syncthreads();

    for (int r = tid; r < NC * WSZ; r += 512) {
        const int ti = r / NC;
        const int ch = r - ti * NC;
        const int ro = (wh * WSZ + ti + SSZ) % IMH;
        float* dst = out + (((size_t)b * NC + ch) * IMH + ro) * IMW;
        const ushort* sp = &sQ[(ti * 8) * 200 + ch];
        float4 a0, a1;
        a0.x = bf2f(sp[0 * 200]);  a0.y = bf2f(sp[1 * 200]);
        a0.z = bf2f(sp[2 * 200]);  a0.w = bf2f(sp[3 * 200]);
        a1.x = bf2f(sp[4 * 200]);  a1.y = bf2f(sp[5 * 200]);
        a1.z = bf2f(sp[6 * 200]);  a1.w = bf2f(sp[7 * 200]);
        *(float4*)(dst + co0) = a0;
        *(float4*)(dst + co4) = a1;
    }
}

extern "C" void kernel_launch(void* const* d_in, const int* in_sizes, int n_in,
                              void* d_out, int out_size, void* d_ws, size_t ws_size,
                              hipStream_t stream) {
    const float* x      = (const float*)d_in[0];
    const float* qkv_w  = (const float*)d_in[1];
    const float* qkv_b  = (const float*)d_in[2];
    const float* proj_w = (const float*)d_in[3];
    const float* proj_b = (const float*)d_in[4];
    const float* bias_t = (const float*)d_in[5];
    float* out = (float*)d_out;
    (void)in_sizes; (void)n_in; (void)out_size;

    ushort* wq_bf = (ushort*)d_ws;                       // 110592 ush
    ushort* wp_bf = wq_bf + WQ_ELEMS;                    // 36864 ush

    hipLaunchKernelGGL(cvt_weights_kernel, dim3((WQ_ELEMS + WP_ELEMS) / 4 / 256), dim3(256),
                       0, stream, qkv_w, proj_w, wq_bf);

    // split-pipeline workspace: weights + qkv (18 planes) + aout
    const size_t QKV_OFF  = (size_t)(WQ_ELEMS + WP_ELEMS);          // ushort offset
    const size_t AOUT_OFF = QKV_OFF + 18 * PLANE;
    const size_t REQ      = (AOUT_OFF + (size_t)TOK_TOTAL * 192) * sizeof(ushort);

    if (ws_size >= REQ) {
        ushort* qkv  = (ushort*)d_ws + QKV_OFF;
        ushort* aout = (ushort*)d_ws + AOUT_OFF;
        hipLaunchKernelGGL(qkv_gemm_kernel, dim3(NB * 576), dim3(256), 0, stream,
                           x, wq_bf, qkv_b, qkv);
        hipLaunchKernelGGL(attn_kernel, dim3(NB * 576 * NHEAD), dim3(256), 0, stream,
                           qkv, bias_t, aout);
        hipLaunchKernelGGL(proj_kernel, dim3(NB * 576), dim3(256), 0, stream,
                           aout, wp_bf, proj_b, out);
    } else {
        hipLaunchKernelGGL(swin_attn_kernel, dim3(NB * NWH * NWW), dim3(512), 0, stream,
                           x, wq_bf, qkv_b, wp_bf, proj_b, bias_t, out);
    }
}